// Round 4
// baseline (189.573 us; speedup 1.0000x reference)
//
#include <hip/hip_runtime.h>
#include <math.h>

typedef unsigned short u16;
typedef short v8s __attribute__((ext_vector_type(8)));
typedef float v4f __attribute__((ext_vector_type(4)));

#define AS1 __attribute__((address_space(1)))
#define AS3 __attribute__((address_space(3)))

__device__ __forceinline__ float bf2f(u16 u) {
    union { unsigned int i; float f; } c; c.i = ((unsigned int)u) << 16; return c.f;
}
__device__ __forceinline__ u16 f2bf(float f) {
    union { float f; unsigned int i; } c; c.f = f;
    unsigned int u = c.i;
    return (u16)((u + 0x7FFFu + ((u >> 16) & 1u)) >> 16);
}
// async global->LDS, 16B per lane. LDS dest = base + lane*16 (wave-uniform base).
__device__ __forceinline__ void gload_lds16(const void* g, void* l) {
    __builtin_amdgcn_global_load_lds((const AS1 void*)(uintptr_t)g,
                                     (AS3 void*)(unsigned int)(uintptr_t)l,
                                     16, 0, 0);
}

#define Nn 32
#define Tt 64
#define Vv 25
#define NP 51200        // N*T*V positions
#define NBLK 400        // M-tiles (51200/128); psum layout [256 d][400 m]

// ---------------------------------------------------------------------------
// prep: bf16 weight transposes + bias2[w][d] + zero pad
// ---------------------------------------------------------------------------
__global__ __launch_bounds__(256) void prep_kernel(
    const float* __restrict__ Wg, const float* __restrict__ Wt,
    const float* __restrict__ A, const float* __restrict__ bg,
    u16* __restrict__ Wgb, u16* __restrict__ Wtb,
    float* __restrict__ bias2, float* __restrict__ zpad)
{
    const int idx = blockIdx.x * 256 + threadIdx.x;
    const int stride = gridDim.x * 256;
    for (int i = idx; i < 256 * 2304; i += stride) {
        int d = i / 2304, r = i - d * 2304, dt = r >> 8, c = r & 255;
        Wtb[i] = f2bf(Wt[(d * 256 + c) * 9 + dt]);
    }
    for (int i = idx; i < 256 * 768; i += stride) {
        int d = i / 768, r = i - d * 768, k = r >> 8, c = r & 255;
        Wgb[i] = f2bf(Wg[(k * 256 + d) * 256 + c]);
    }
    for (int i = idx; i < 25 * 256; i += stride) {
        int w = i >> 8, d = i & 255;
        float s = 0.f;
        for (int k = 0; k < 3; ++k) {
            float cs = 0.f;
            for (int v = 0; v < 25; ++v) cs += A[(k * 25 + v) * 25 + w];
            s += bg[k * 256 + d] * cs;
        }
        bias2[i] = s;
    }
    for (int i = idx; i < 256; i += stride) zpad[i] = 0.f;
}

// ---------------------------------------------------------------------------
// xa2[p=(n,t,w)][k*256+c] = sum_v x[n,c,t,v] * A[k,v,w]   (bf16 out)
// Thread = c; x-row in registers; A reads wave-uniform (s_load).
// ---------------------------------------------------------------------------
__global__ __launch_bounds__(256) void xa_kernel(
    const float* __restrict__ x, const float* __restrict__ A,
    u16* __restrict__ xa2)
{
    const int t = blockIdx.x, n = blockIdx.y;
    const int tid = threadIdx.x;              // = c
    __shared__ float xs[256 * 25];            // 25.6 KB

    for (int i = tid; i < 6400; i += 256) {
        int c = i / 25, v = i - c * 25;
        xs[i] = x[((n * 256 + c) * 64 + t) * 25 + v];
    }
    __syncthreads();

    float xr[25];
    #pragma unroll
    for (int v = 0; v < 25; ++v) xr[v] = xs[tid * 25 + v];

    const size_t pbase = ((size_t)n * 64 + t) * 25;
    #pragma unroll 1
    for (int k = 0; k < 3; ++k) {
        float o[25];
        #pragma unroll
        for (int w = 0; w < 25; ++w) {
            float acc = 0.f;
            #pragma unroll
            for (int v = 0; v < 25; ++v)
                acc = fmaf(xr[v], A[(k * 25 + v) * 25 + w], acc);
            o[w] = acc;
        }
        u16* dst = xa2 + k * 256 + tid;
        #pragma unroll
        for (int w = 0; w < 25; ++w)
            dst[(pbase + w) * 768] = f2bf(o[w]);
    }
}

// ---------------------------------------------------------------------------
// GEMM, 128x128 tile, 256 threads (4 waves 2Mx2N, per-wave 64x64), BK=64,
// double-buffered LDS (2 x 32KB) with counted-vmcnt prefetch (T4):
//   reads+MFMA(buf) -> barrier -> STAGE(buf, kt+2) -> vmcnt(8) -> barrier
// Grid: 800 blocks = [2 N-halves][400 M-tiles], bijective XCD swizzle.
// TCN=true: A rows are t-shifted y2T reads (zero-pad at t edges); epilogue
// emits bf16 z + deterministic per-(d, m-tile) BN partials.
// ---------------------------------------------------------------------------
template<int KTOT, bool TCN>
__global__ __launch_bounds__(256, 2) void gemm_kernel(
    const u16* __restrict__ Ad, const u16* __restrict__ Bw,
    const float* __restrict__ bias, u16* __restrict__ outB,
    float* __restrict__ psum, float* __restrict__ psq,
    const u16* __restrict__ zpad)
{
    constexpr int NT = KTOT / 64;
    __shared__ u16 smem[2][16384];           // 2 x (A 16KB | B 16KB) = 64KB

    const int tid = threadIdx.x;
    const int wid = tid >> 6, lane = tid & 63;
    const int lr = lane & 15, hk = lane >> 4;
    const int wm = wid >> 1, wn = wid & 1;
    const int rA = lane >> 3, sA = lane & 7;

    // XCD swizzle (800 % 8 == 0 -> simple form bijective); contiguous m-range
    // with a single N-half per XCD chunk so the B-half stays L2-resident.
    const int orig = blockIdx.x;
    const int swz = (orig & 7) * 100 + (orig >> 3);
    const int nh = swz / 400, m = swz % 400;
    const int d0 = nh * 128;

    v4f acc[4][4];
    const v4f vzero = {0.f, 0.f, 0.f, 0.f};
    #pragma unroll
    for (int mf = 0; mf < 4; ++mf)
        #pragma unroll
        for (int nf = 0; nf < 4; ++nf) acc[mf][nf] = vzero;

    // STAGE: 8 gload_lds/thread (A: 4 chunks, B: 4 chunks; chunk = 8 rows x 128B)
#define STAGE(buf, ktv)                                                        \
    {                                                                          \
        _Pragma("unroll")                                                      \
        for (int i = 0; i < 4; ++i) {                                          \
            const int ch = wid + i * 4;                                        \
            const int row = ch * 8 + rA;                                       \
            const int ss = sA ^ (row & 7);                                     \
            const u16* srcA;                                                   \
            if (TCN) {                                                         \
                const int dt = (ktv) >> 2, c0 = ((ktv)&3) << 6;                \
                const int p = m * 128 + row;                                   \
                const int tv = p % 1600, t = tv / 25;                          \
                const int tp = t + dt - 4;                                     \
                srcA = ((unsigned)tp < 64u)                                    \
                     ? (Ad + (size_t)(p + (dt - 4) * 25) * 256 + c0 + ss * 8)  \
                     : zpad;                                                   \
            } else {                                                           \
                srcA = Ad + (size_t)(m * 128 + row) * 768 + (ktv)*64 + ss * 8; \
            }                                                                  \
            gload_lds16(srcA, (char*)&smem[buf][0] + ch * 1024);               \
            gload_lds16(Bw + (size_t)(d0 + row) * KTOT + (ktv)*64 + ss * 8,    \
                        (char*)&smem[buf][8192] + ch * 1024);                  \
        }                                                                      \
    }

    STAGE(0, 0);
    STAGE(1, 1);
    asm volatile("s_waitcnt vmcnt(8)" ::: "memory");   // tile 0 landed
    __builtin_amdgcn_s_barrier();

    #pragma unroll 2
    for (int kt = 0; kt < NT; ++kt) {
        const int cur = kt & 1;
        const u16* As = &smem[cur][0];
        const u16* Bs = &smem[cur][8192];
        v8s a[4][2], b[4][2];
        #pragma unroll
        for (int mf = 0; mf < 4; ++mf)
            #pragma unroll
            for (int kk = 0; kk < 2; ++kk) {
                const int row = wm * 64 + mf * 16 + lr;
                const int slot = kk * 4 + hk;
                a[mf][kk] = *(const v8s*)((const char*)As + row * 128 + ((slot ^ (row & 7)) << 4));
            }
        #pragma unroll
        for (int nf = 0; nf < 4; ++nf)
            #pragma unroll
            for (int kk = 0; kk < 2; ++kk) {
                const int row = wn * 64 + nf * 16 + lr;
                const int slot = kk * 4 + hk;
                b[nf][kk] = *(const v8s*)((const char*)Bs + row * 128 + ((slot ^ (row & 7)) << 4));
            }
        #pragma unroll
        for (int kk = 0; kk < 2; ++kk)
            #pragma unroll
            for (int mf = 0; mf < 4; ++mf)
                #pragma unroll
                for (int nf = 0; nf < 4; ++nf)
                    acc[mf][nf] = __builtin_amdgcn_mfma_f32_16x16x32_bf16(
                        a[mf][kk], b[nf][kk], acc[mf][nf], 0, 0, 0);
        __builtin_amdgcn_sched_barrier(0);
        __builtin_amdgcn_s_barrier();            // all waves done reading buf[cur]
        if (kt + 2 < NT) {
            STAGE(cur, kt + 2);                  // overwrite freed buffer
            asm volatile("s_waitcnt vmcnt(8)" ::: "memory");  // tile kt+1 landed
        } else {
            asm volatile("s_waitcnt vmcnt(0)" ::: "memory");  // tail drain
        }
        __builtin_amdgcn_s_barrier();            // buf[cur^1] ready for all
    }
#undef STAGE

    // ---- epilogue ----
    if (!TCN) {
        #pragma unroll
        for (int mf = 0; mf < 4; ++mf) {
            #pragma unroll
            for (int j = 0; j < 4; ++j) {
                const int p = m * 128 + wm * 64 + mf * 16 + hk * 4 + j;
                const int w = p % 25;
                #pragma unroll
                for (int nf = 0; nf < 4; ++nf) {
                    const int d = d0 + wn * 64 + nf * 16 + lr;
                    outB[(size_t)p * 256 + d] = f2bf(acc[mf][nf][j] + bias[w * 256 + d]);
                }
            }
        }
    } else {
        float s[4], q[4];
        #pragma unroll
        for (int nf = 0; nf < 4; ++nf) {
            const int d = d0 + wn * 64 + nf * 16 + lr;
            const float bb = bias[d];
            s[nf] = 0.f; q[nf] = 0.f;
            #pragma unroll
            for (int mf = 0; mf < 4; ++mf) {
                #pragma unroll
                for (int j = 0; j < 4; ++j) {
                    const int p = m * 128 + wm * 64 + mf * 16 + hk * 4 + j;
                    const float zz = acc[mf][nf][j] + bb;
                    outB[(size_t)p * 256 + d] = f2bf(zz);
                    s[nf] += zz; q[nf] += zz * zz;
                }
            }
            s[nf] += __shfl_xor(s[nf], 16); s[nf] += __shfl_xor(s[nf], 32);
            q[nf] += __shfl_xor(q[nf], 16); q[nf] += __shfl_xor(q[nf], 32);
        }
        float* red = (float*)&smem[0][0];    // [2 wm][128 dl] s, then q
        if (hk == 0) {
            #pragma unroll
            for (int nf = 0; nf < 4; ++nf) {
                const int dl = wn * 64 + nf * 16 + lr;
                red[wm * 128 + dl] = s[nf];
                red[256 + wm * 128 + dl] = q[nf];
            }
        }
        __syncthreads();
        if (tid < 128) {
            psum[(size_t)(d0 + tid) * NBLK + m] = red[tid] + red[128 + tid];
            psq[(size_t)(d0 + tid) * NBLK + m]  = red[256 + tid] + red[384 + tid];
        }
    }
}

// ---------------------------------------------------------------------------
// BN stats: reduce 400 m-tile partials per channel -> scale/shift
// ---------------------------------------------------------------------------
__global__ __launch_bounds__(256) void bn_stats_kernel(
    const float* __restrict__ psum, const float* __restrict__ psq,
    const float* __restrict__ gamma, const float* __restrict__ beta,
    float* __restrict__ scale, float* __restrict__ shift)
{
    const int d = blockIdx.x, tid = threadIdx.x;
    float s = 0.f, q = 0.f;
    for (int i = tid; i < NBLK; i += 256) {
        s += psum[(size_t)d * NBLK + i];
        q += psq[(size_t)d * NBLK + i];
    }
    #pragma unroll
    for (int off = 32; off; off >>= 1) {
        s += __shfl_down(s, off);
        q += __shfl_down(q, off);
    }
    __shared__ float rs[4], rq[4];
    if ((tid & 63) == 0) { rs[tid >> 6] = s; rq[tid >> 6] = q; }
    __syncthreads();
    if (tid == 0) {
        s = rs[0] + rs[1] + rs[2] + rs[3];
        q = rq[0] + rq[1] + rq[2] + rq[3];
        const float mean = s / 51200.f;
        const float var = q / 51200.f - mean * mean;
        const float inv = rsqrtf(var + 1e-5f);
        scale[d] = gamma[d] * inv;
        shift[d] = beta[d] - gamma[d] * inv * mean;
    }
}

// ---------------------------------------------------------------------------
// out[n,d,tv] = relu(z[p][d]*scale[d]+shift[d] + x[n,d,tv]); LDS transpose.
// ---------------------------------------------------------------------------
__global__ __launch_bounds__(256) void bn_apply_kernel(
    const u16* __restrict__ zb, const float* __restrict__ x,
    const float* __restrict__ scale, const float* __restrict__ shift,
    float* __restrict__ out)
{
    const int chunk = blockIdx.x;   // 0..24
    const int n = blockIdx.y;       // 0..31
    const int tid = threadIdx.x;
    __shared__ u16 zs[128 * 66];    // 16.9 KB, padded rows
    const size_t p0 = (size_t)n * 1600 + chunk * 64;

    for (int half = 0; half < 2; ++half) {
        const int d0 = half * 128;
        if (half) __syncthreads();
        for (int i = tid; i < 128 * 64; i += 256) {
            const int pl = i >> 7, dl = i & 127;
            zs[dl * 66 + pl] = zb[(p0 + pl) * 256 + d0 + dl];
        }
        __syncthreads();
        for (int i = tid; i < 128 * 64; i += 256) {
            const int dl = i >> 6, j = i & 63;
            const int d = d0 + dl;
            const size_t addr = ((size_t)n * 256 + d) * 1600 + chunk * 64 + j;
            const float r = bf2f(zs[dl * 66 + j]) * scale[d] + shift[d] + x[addr];
            out[addr] = fmaxf(r, 0.f);
        }
    }
}

extern "C" void kernel_launch(void* const* d_in, const int* in_sizes, int n_in,
                              void* d_out, int out_size, void* d_ws, size_t ws_size,
                              hipStream_t stream)
{
    const float* x     = (const float*)d_in[0];
    const float* A     = (const float*)d_in[1];
    const float* Wg    = (const float*)d_in[2];
    const float* bg    = (const float*)d_in[3];
    const float* Wt    = (const float*)d_in[4];
    const float* bt    = (const float*)d_in[5];
    const float* gamma = (const float*)d_in[6];
    const float* beta  = (const float*)d_in[7];
    float* out = (float*)d_out;

    char* w = (char*)d_ws;
    u16*   xa2   = (u16*)(w);                    // 78,643,200 B
    u16*   y2T   = (u16*)(w + 78643200);         // 26,214,400 B
    u16*   zb    = (u16*)(w + 104857600);        // 26,214,400 B
    u16*   Wgb   = (u16*)(w + 131072000);        //    393,216 B
    u16*   Wtb   = (u16*)(w + 131465216);        //  1,179,648 B
    float* bias2 = (float*)(w + 132644864);      //     25,600 B
    float* psum  = (float*)(w + 132670464);      //    409,600 B
    float* psq   = (float*)(w + 133080064);      //    409,600 B
    float* scale = (float*)(w + 133489664);      //      1,024 B
    float* shift = (float*)(w + 133490688);      //      1,024 B
    float* zpad  = (float*)(w + 133491712);      //      1,024 B (zeroed)

    prep_kernel<<<512, 256, 0, stream>>>(Wg, Wt, A, bg, Wgb, Wtb, bias2, zpad);
    xa_kernel<<<dim3(64, 32), 256, 0, stream>>>(x, A, xa2);
    gemm_kernel<768, false><<<800, 256, 0, stream>>>(xa2, Wgb, bias2, y2T,
                                                     nullptr, nullptr, (const u16*)zpad);
    gemm_kernel<2304, true><<<800, 256, 0, stream>>>(y2T, Wtb, bt, zb,
                                                     psum, psq, (const u16*)zpad);
    bn_stats_kernel<<<256, 256, 0, stream>>>(psum, psq, gamma, beta, scale, shift);
    bn_apply_kernel<<<dim3(25, 32), 256, 0, stream>>>(zb, x, scale, shift, out);
}

// Round 5
// 167.276 us; speedup vs baseline: 1.1333x; 1.1333x over previous
//
#include <hip/hip_runtime.h>
#include <math.h>

typedef unsigned short u16;
typedef short v8s __attribute__((ext_vector_type(8)));
typedef float v4f __attribute__((ext_vector_type(4)));

#define AS1 __attribute__((address_space(1)))
#define AS3 __attribute__((address_space(3)))

__device__ __forceinline__ float bf2f(u16 u) {
    union { unsigned int i; float f; } c; c.i = ((unsigned int)u) << 16; return c.f;
}
__device__ __forceinline__ u16 f2bf(float f) {
    union { float f; unsigned int i; } c; c.f = f;
    unsigned int u = c.i;
    return (u16)((u + 0x7FFFu + ((u >> 16) & 1u)) >> 16);
}
// async global->LDS, 16B per lane. LDS dest = base + lane*16 (wave-uniform base).
__device__ __forceinline__ void gload_lds16(const void* g, void* l) {
    __builtin_amdgcn_global_load_lds((const AS1 void*)(uintptr_t)g,
                                     (AS3 void*)(unsigned int)(uintptr_t)l,
                                     16, 0, 0);
}

#define Nn 32
#define Tt 64
#define Vv 25
#define NP 51200        // N*T*V positions
#define NBLK 200        // M-tiles (51200/256); psum layout [256 d][200 m]

// ---------------------------------------------------------------------------
// prep: bf16 weight transposes + bias2[w][d] + zero pad
// ---------------------------------------------------------------------------
__global__ __launch_bounds__(256) void prep_kernel(
    const float* __restrict__ Wg, const float* __restrict__ Wt,
    const float* __restrict__ A, const float* __restrict__ bg,
    u16* __restrict__ Wgb, u16* __restrict__ Wtb,
    float* __restrict__ bias2, float* __restrict__ zpad)
{
    const int idx = blockIdx.x * 256 + threadIdx.x;
    const int stride = gridDim.x * 256;
    for (int i = idx; i < 256 * 2304; i += stride) {
        int d = i / 2304, r = i - d * 2304, dt = r >> 8, c = r & 255;
        Wtb[i] = f2bf(Wt[(d * 256 + c) * 9 + dt]);
    }
    for (int i = idx; i < 256 * 768; i += stride) {
        int d = i / 768, r = i - d * 768, k = r >> 8, c = r & 255;
        Wgb[i] = f2bf(Wg[(k * 256 + d) * 256 + c]);
    }
    for (int i = idx; i < 25 * 256; i += stride) {
        int w = i >> 8, d = i & 255;
        float s = 0.f;
        for (int k = 0; k < 3; ++k) {
            float cs = 0.f;
            for (int v = 0; v < 25; ++v) cs += A[(k * 25 + v) * 25 + w];
            s += bg[k * 256 + d] * cs;
        }
        bias2[i] = s;
    }
    for (int i = idx; i < 256; i += stride) zpad[i] = 0.f;
}

// ---------------------------------------------------------------------------
// xa2[p=(n,t,w)][k*256+c] = sum_v x[n,c,t,v] * A[k,v,w]   (bf16 out)
// Thread = c; x-row in registers; A reads wave-uniform (s_load).
// ---------------------------------------------------------------------------
__global__ __launch_bounds__(256) void xa_kernel(
    const float* __restrict__ x, const float* __restrict__ A,
    u16* __restrict__ xa2)
{
    const int t = blockIdx.x, n = blockIdx.y;
    const int tid = threadIdx.x;              // = c
    __shared__ float xs[256 * 25];            // 25.6 KB

    for (int i = tid; i < 6400; i += 256) {
        int c = i / 25, v = i - c * 25;
        xs[i] = x[((n * 256 + c) * 64 + t) * 25 + v];
    }
    __syncthreads();

    float xr[25];
    #pragma unroll
    for (int v = 0; v < 25; ++v) xr[v] = xs[tid * 25 + v];

    const size_t pbase = ((size_t)n * 64 + t) * 25;
    #pragma unroll 1
    for (int k = 0; k < 3; ++k) {
        float o[25];
        #pragma unroll
        for (int w = 0; w < 25; ++w) {
            float acc = 0.f;
            #pragma unroll
            for (int v = 0; v < 25; ++v)
                acc = fmaf(xr[v], A[(k * 25 + v) * 25 + w], acc);
            o[w] = acc;
        }
        u16* dst = xa2 + k * 256 + tid;
        #pragma unroll
        for (int w = 0; w < 25; ++w)
            dst[(pbase + w) * 768] = f2bf(o[w]);
    }
}

// ---------------------------------------------------------------------------
// GEMM, 256x256 tile (BN = full N), BK=64, 512 threads = 8 waves (2M x 4N),
// per-wave 128x64 out = 8x4 frags of 16x16x32 bf16 MFMA.
// 4-phase K-tile schedule (T3/T4 regime): each phase = {2 prefetch gloads ||
// ds_read one frag quadrant || setprio(1) 16-MFMA cluster}; ONE
// __syncthreads per K-tile, whose vmcnt(0) drain is covered by phases 2-3.
// LDS: 2 x (A 32KB | B 32KB) = 128KB double buffer. Grid = 200 m-tiles.
// XOR-swizzle: inverse-swizzled GLOBAL source + swizzled ds_read (rule 21).
// TCN=true: A rows are t-shifted y2T reads (zero-pad at t edges); epilogue
// emits bf16 z + deterministic per-(d, m-tile) BN partials.
// ---------------------------------------------------------------------------
template<int KTOT, bool TCN>
__global__ __launch_bounds__(512) void gemm_kernel(
    const u16* __restrict__ Ad, const u16* __restrict__ Bw,
    const float* __restrict__ bias, u16* __restrict__ outB,
    float* __restrict__ psum, float* __restrict__ psq,
    const u16* __restrict__ zpad)
{
    constexpr int NT = KTOT / 64;
    __shared__ u16 smem[2][32768];           // 128 KB: 2 x (A 32KB | B 32KB)

    const int tid = threadIdx.x;
    const int wid = tid >> 6, lane = tid & 63;
    const int lr = lane & 15, hk = lane >> 4;
    const int wm = wid >> 2, wn = wid & 3;   // 2M x 4N wave grid
    const int rA = lane >> 3, sA = lane & 7;

    // bijective XCD swizzle (200 % 8 == 0)
    const int orig = blockIdx.x;
    const int m = (orig & 7) * 25 + (orig >> 3);

    v4f acc[8][4];
    const v4f vzero = {0.f, 0.f, 0.f, 0.f};
    #pragma unroll
    for (int mf = 0; mf < 8; ++mf)
        #pragma unroll
        for (int nf = 0; nf < 4; ++nf) acc[mf][nf] = vzero;

    // one block-wide staging call: A chunk + B chunk (chunk = 8 rows x 128B)
#define STAGE2(bufp, ktv, i)                                                   \
    {                                                                          \
        const int ch = (i) * 8 + wid;                                          \
        const int row = ch * 8 + rA;                                           \
        const int ss = sA ^ rA; /* row&7 == rA */                              \
        const u16* srcA;                                                       \
        if (TCN) {                                                             \
            const int dt = (ktv) >> 2, c0 = ((ktv)&3) << 6;                    \
            const int p = m * 256 + row;                                       \
            const int t = (p % 1600) / 25;                                     \
            const int tp = t + dt - 4;                                         \
            srcA = ((unsigned)tp < 64u)                                        \
                 ? (Ad + (size_t)(p + (dt - 4) * 25) * 256 + c0 + ss * 8)      \
                 : zpad;                                                       \
        } else {                                                               \
            srcA = Ad + (size_t)(m * 256 + row) * 768 + (ktv)*64 + ss * 8;     \
        }                                                                      \
        gload_lds16(srcA, (char*)(bufp) + ch * 1024);                          \
        gload_lds16(Bw + (size_t)row * KTOT + (ktv)*64 + ss * 8,               \
                    (char*)(bufp) + 32768 + ch * 1024);                        \
    }

#define LDA_(dst, mfv, kkv)                                                    \
    {                                                                          \
        const int row = wm * 128 + (mfv)*16 + lr;                              \
        dst = *(const v8s*)((const char*)As + row * 128 +                      \
                            ((((kkv)*4 + hk) ^ (row & 7)) << 4));              \
    }
#define LDB_(dst, nfv, kkv)                                                    \
    {                                                                          \
        const int row = wn * 64 + (nfv)*16 + lr;                               \
        dst = *(const v8s*)((const char*)Bs + row * 128 +                      \
                            ((((kkv)*4 + hk) ^ (row & 7)) << 4));              \
    }

    // prologue: stage tile 0
    #pragma unroll
    for (int i = 0; i < 4; ++i) STAGE2(&smem[0][0], 0, i);
    __syncthreads();

    #pragma unroll 1
    for (int kt = 0; kt < NT; ++kt) {
        const u16* As = &smem[kt & 1][0];
        const u16* Bs = As + 16384;
        u16* nbuf = &smem[(kt + 1) & 1][0];
        const bool pf = (kt + 1 < NT);
        v8s aL[4], aH[4], b0[4], b1[4];

        // ---- phase 0: prefetch calls 0,1 | read b kk0 + a[0..3] kk0 | MFMA
        if (pf) { STAGE2(nbuf, kt + 1, 0); STAGE2(nbuf, kt + 1, 1); }
        #pragma unroll
        for (int nf = 0; nf < 4; ++nf) LDB_(b0[nf], nf, 0);
        #pragma unroll
        for (int mf = 0; mf < 4; ++mf) LDA_(aL[mf], mf, 0);
        __builtin_amdgcn_s_setprio(1);
        #pragma unroll
        for (int mf = 0; mf < 4; ++mf)
            #pragma unroll
            for (int nf = 0; nf < 4; ++nf)
                acc[mf][nf] = __builtin_amdgcn_mfma_f32_16x16x32_bf16(
                    aL[mf], b0[nf], acc[mf][nf], 0, 0, 0);
        __builtin_amdgcn_s_setprio(0);
        __builtin_amdgcn_sched_barrier(0);

        // ---- phase 1: prefetch calls 2,3 | read a[4..7] kk0 | MFMA
        if (pf) { STAGE2(nbuf, kt + 1, 2); STAGE2(nbuf, kt + 1, 3); }
        #pragma unroll
        for (int mf = 0; mf < 4; ++mf) LDA_(aH[mf], mf + 4, 0);
        __builtin_amdgcn_s_setprio(1);
        #pragma unroll
        for (int mf = 0; mf < 4; ++mf)
            #pragma unroll
            for (int nf = 0; nf < 4; ++nf)
                acc[mf + 4][nf] = __builtin_amdgcn_mfma_f32_16x16x32_bf16(
                    aH[mf], b0[nf], acc[mf + 4][nf], 0, 0, 0);
        __builtin_amdgcn_s_setprio(0);
        __builtin_amdgcn_sched_barrier(0);

        // ---- phase 2: read b kk1 + a[0..3] kk1 | MFMA
        #pragma unroll
        for (int nf = 0; nf < 4; ++nf) LDB_(b1[nf], nf, 1);
        #pragma unroll
        for (int mf = 0; mf < 4; ++mf) LDA_(aL[mf], mf, 1);
        __builtin_amdgcn_s_setprio(1);
        #pragma unroll
        for (int mf = 0; mf < 4; ++mf)
            #pragma unroll
            for (int nf = 0; nf < 4; ++nf)
                acc[mf][nf] = __builtin_amdgcn_mfma_f32_16x16x32_bf16(
                    aL[mf], b1[nf], acc[mf][nf], 0, 0, 0);
        __builtin_amdgcn_s_setprio(0);
        __builtin_amdgcn_sched_barrier(0);

        // ---- phase 3: read a[4..7] kk1 | MFMA
        #pragma unroll
        for (int mf = 0; mf < 4; ++mf) LDA_(aH[mf], mf + 4, 1);
        __builtin_amdgcn_s_setprio(1);
        #pragma unroll
        for (int mf = 0; mf < 4; ++mf)
            #pragma unroll
            for (int nf = 0; nf < 4; ++nf)
                acc[mf + 4][nf] = __builtin_amdgcn_mfma_f32_16x16x32_bf16(
                    aH[mf], b1[nf], acc[mf + 4][nf], 0, 0, 0);
        __builtin_amdgcn_s_setprio(0);

        // vmcnt(0)+lgkmcnt(0)+barrier: prefetch (issued phases 0-1) drained
        // here, after ~2 phases of MFMA cover; collective across waves.
        __syncthreads();
    }
#undef STAGE2
#undef LDA_
#undef LDB_

    // ---- epilogue ----
    if (!TCN) {
        #pragma unroll
        for (int mf = 0; mf < 8; ++mf) {
            #pragma unroll
            for (int j = 0; j < 4; ++j) {
                const int p = m * 256 + wm * 128 + mf * 16 + hk * 4 + j;
                const int w = p % 25;
                #pragma unroll
                for (int nf = 0; nf < 4; ++nf) {
                    const int d = wn * 64 + nf * 16 + lr;
                    outB[(size_t)p * 256 + d] = f2bf(acc[mf][nf][j] + bias[w * 256 + d]);
                }
            }
        }
    } else {
        float s[4], q[4];
        #pragma unroll
        for (int nf = 0; nf < 4; ++nf) {
            const int d = wn * 64 + nf * 16 + lr;
            const float bb = bias[d];
            s[nf] = 0.f; q[nf] = 0.f;
            #pragma unroll
            for (int mf = 0; mf < 8; ++mf) {
                #pragma unroll
                for (int j = 0; j < 4; ++j) {
                    const int p = m * 256 + wm * 128 + mf * 16 + hk * 4 + j;
                    const float zz = acc[mf][nf][j] + bb;
                    outB[(size_t)p * 256 + d] = f2bf(zz);
                    s[nf] += zz; q[nf] += zz * zz;
                }
            }
            s[nf] += __shfl_xor(s[nf], 16); s[nf] += __shfl_xor(s[nf], 32);
            q[nf] += __shfl_xor(q[nf], 16); q[nf] += __shfl_xor(q[nf], 32);
        }
        __syncthreads();
        float* red = (float*)&smem[0][0];    // [2 wm][256 d] s, then q
        if (hk == 0) {
            #pragma unroll
            for (int nf = 0; nf < 4; ++nf) {
                const int d = wn * 64 + nf * 16 + lr;
                red[wm * 256 + d] = s[nf];
                red[512 + wm * 256 + d] = q[nf];
            }
        }
        __syncthreads();
        if (tid < 256) {
            psum[(size_t)tid * NBLK + m] = red[tid] + red[256 + tid];
            psq[(size_t)tid * NBLK + m]  = red[512 + tid] + red[768 + tid];
        }
    }
}

// ---------------------------------------------------------------------------
// BN stats: reduce 200 m-tile partials per channel -> scale/shift
// ---------------------------------------------------------------------------
__global__ __launch_bounds__(256) void bn_stats_kernel(
    const float* __restrict__ psum, const float* __restrict__ psq,
    const float* __restrict__ gamma, const float* __restrict__ beta,
    float* __restrict__ scale, float* __restrict__ shift)
{
    const int d = blockIdx.x, tid = threadIdx.x;
    float s = 0.f, q = 0.f;
    for (int i = tid; i < NBLK; i += 256) {
        s += psum[(size_t)d * NBLK + i];
        q += psq[(size_t)d * NBLK + i];
    }
    #pragma unroll
    for (int off = 32; off; off >>= 1) {
        s += __shfl_down(s, off);
        q += __shfl_down(q, off);
    }
    __shared__ float rs[4], rq[4];
    if ((tid & 63) == 0) { rs[tid >> 6] = s; rq[tid >> 6] = q; }
    __syncthreads();
    if (tid == 0) {
        s = rs[0] + rs[1] + rs[2] + rs[3];
        q = rq[0] + rq[1] + rq[2] + rq[3];
        const float mean = s / 51200.f;
        const float var = q / 51200.f - mean * mean;
        const float inv = rsqrtf(var + 1e-5f);
        scale[d] = gamma[d] * inv;
        shift[d] = beta[d] - gamma[d] * inv * mean;
    }
}

// ---------------------------------------------------------------------------
// out[n,d,tv] = relu(z[p][d]*scale[d]+shift[d] + x[n,d,tv]); LDS transpose.
// ---------------------------------------------------------------------------
__global__ __launch_bounds__(256) void bn_apply_kernel(
    const u16* __restrict__ zb, const float* __restrict__ x,
    const float* __restrict__ scale, const float* __restrict__ shift,
    float* __restrict__ out)
{
    const int chunk = blockIdx.x;   // 0..24
    const int n = blockIdx.y;       // 0..31
    const int tid = threadIdx.x;
    __shared__ u16 zs[128 * 66];    // 16.9 KB, padded rows
    const size_t p0 = (size_t)n * 1600 + chunk * 64;

    for (int half = 0; half < 2; ++half) {
        const int d0 = half * 128;
        if (half) __syncthreads();
        for (int i = tid; i < 128 * 64; i += 256) {
            const int pl = i >> 7, dl = i & 127;
            zs[dl * 66 + pl] = zb[(p0 + pl) * 256 + d0 + dl];
        }
        __syncthreads();
        for (int i = tid; i < 128 * 64; i += 256) {
            const int dl = i >> 6, j = i & 63;
            const int d = d0 + dl;
            const size_t addr = ((size_t)n * 256 + d) * 1600 + chunk * 64 + j;
            const float r = bf2f(zs[dl * 66 + j]) * scale[d] + shift[d] + x[addr];
            out[addr] = fmaxf(r, 0.f);
        }
    }
}

extern "C" void kernel_launch(void* const* d_in, const int* in_sizes, int n_in,
                              void* d_out, int out_size, void* d_ws, size_t ws_size,
                              hipStream_t stream)
{
    const float* x     = (const float*)d_in[0];
    const float* A     = (const float*)d_in[1];
    const float* Wg    = (const float*)d_in[2];
    const float* bg    = (const float*)d_in[3];
    const float* Wt    = (const float*)d_in[4];
    const float* bt    = (const float*)d_in[5];
    const float* gamma = (const float*)d_in[6];
    const float* beta  = (const float*)d_in[7];
    float* out = (float*)d_out;

    char* w = (char*)d_ws;
    u16*   xa2   = (u16*)(w);                    // 78,643,200 B
    u16*   y2T   = (u16*)(w + 78643200);         // 26,214,400 B
    u16*   zb    = (u16*)(w + 104857600);        // 26,214,400 B
    u16*   Wgb   = (u16*)(w + 131072000);        //    393,216 B
    u16*   Wtb   = (u16*)(w + 131465216);        //  1,179,648 B
    float* bias2 = (float*)(w + 132644864);      //     25,600 B
    float* psum  = (float*)(w + 132670464);      //    204,800 B
    float* psq   = (float*)(w + 133080064);      //    204,800 B
    float* scale = (float*)(w + 133489664);      //      1,024 B
    float* shift = (float*)(w + 133490688);      //      1,024 B
    float* zpad  = (float*)(w + 133491712);      //      1,024 B (zeroed)

    prep_kernel<<<512, 256, 0, stream>>>(Wg, Wt, A, bg, Wgb, Wtb, bias2, zpad);
    xa_kernel<<<dim3(64, 32), 256, 0, stream>>>(x, A, xa2);
    gemm_kernel<768, false><<<NBLK, 512, 0, stream>>>(xa2, Wgb, bias2, y2T,
                                                      nullptr, nullptr, (const u16*)zpad);
    gemm_kernel<2304, true><<<NBLK, 512, 0, stream>>>(y2T, Wtb, bt, zb,
                                                      psum, psq, (const u16*)zpad);
    bn_stats_kernel<<<256, 256, 0, stream>>>(psum, psq, gamma, beta, scale, shift);
    bn_apply_kernel<<<dim3(25, 32), 256, 0, stream>>>(zb, x, scale, shift, out);
}